// Round 1
// baseline (274.492 us; speedup 1.0000x reference)
//
#include <hip/hip_runtime.h>
#include <hip/hip_bf16.h>
#include <stdint.h>

#define IN_F   4096
#define OUT_F  768
#define NBITS  8
#define OUTB   (OUT_F * NBITS)   // 6144
#define BATCH  1024

typedef short short8  __attribute__((ext_vector_type(8)));
typedef float f32x4   __attribute__((ext_vector_type(4)));

__device__ __forceinline__ ushort f2bf(float f) {
    uint32_t u = __builtin_bit_cast(uint32_t, f);
    u += 0x7FFFu + ((u >> 16) & 1u);   // round-to-nearest-even
    return (ushort)(u >> 16);
}

__device__ __forceinline__ float waveReduceSum(float v) {
    #pragma unroll
    for (int off = 32; off > 0; off >>= 1) v += __shfl_down(v, off, 64);
    return v;
}

__global__ void k_init(float* accum) {
    accum[0] = 0.f;   // recon sum
    accum[1] = 0.f;   // reg sum
}

// Kernel B: int_weights (bf16, packed [k/8][n][k%8]) + reg_loss partial sums.
// Thread handles 8 consecutive k (rows) for one output column o.
__global__ __launch_bounds__(256) void k_weights(const float* __restrict__ w,
                                                 ushort* __restrict__ wp,
                                                 float* __restrict__ accum) {
    int t  = blockIdx.x * 256 + threadIdx.x;     // 512*768 threads
    int o  = t % OUT_F;
    int i8 = t / OUT_F;                          // k-group (8 rows)
    const float* src = w + (size_t)(i8 * 8) * OUTB + (size_t)o * 8;

    const float P[8] = {1.f, 2.f, 4.f, 8.f, 16.f, 32.f, 64.f, -128.f};
    float regsum = 0.f;
    union { ushort u[8]; uint4 v; } pk;

    #pragma unroll
    for (int r = 0; r < 8; r++) {
        float4 a = *(const float4*)(src + (size_t)r * OUTB);
        float4 b = *(const float4*)(src + (size_t)r * OUTB + 4);
        float x[8] = {a.x, a.y, a.z, a.w, b.x, b.y, b.z, b.w};
        float iw = 0.f;
        #pragma unroll
        for (int j = 0; j < 8; j++) {
            float p = 1.f / (1.f + __expf(-x[j]));
            iw += p * P[j];
            regsum += fminf(p, 1.f - p);
        }
        pk.u[r] = f2bf(iw);
    }
    // packed layout: wp[(k/8)*OUT_F*8 + n*8 + k%8]
    *(uint4*)(wp + ((size_t)i8 * OUT_F + o) * 8) = pk.v;

    // reduce regsum: wave -> block -> atomic
    float ws = waveReduceSum(regsum);
    __shared__ float red[4];
    int lane = threadIdx.x & 63, wv = threadIdx.x >> 6;
    if (lane == 0) red[wv] = ws;
    __syncthreads();
    if (threadIdx.x == 0) {
        float s = red[0] + red[1] + red[2] + red[3];
        atomicAdd(accum + 1, s);
    }
}

// Kernel C: pred = latent @ int_weights via bf16 MFMA, fused int_sum + recon reduction.
// Block tile 64x64, 4 waves in 2x2, each wave 2x2 frags of 16x16x32. BK=32.
__global__ __launch_bounds__(256) void k_gemm(const float* __restrict__ latent,
                                              const ushort* __restrict__ wp,
                                              const float* __restrict__ tsum,
                                              float* __restrict__ accum) {
    __shared__ ushort lA[64 * 40];      // [row][k] padded to 40 (2-way max aliasing)
    __shared__ ushort lB[4 * 64 * 8];   // [kg][n][j] — contiguous copy of packed W

    const int tid  = threadIdx.x;
    const int n0   = blockIdx.x * 64;
    const int m0   = blockIdx.y * 64;
    const int lane = tid & 63, wv = tid >> 6;
    const int wm = wv >> 1, wn = wv & 1;
    const int quad = lane >> 4, l16 = lane & 15;

    f32x4 acc[2][2] = {{{0.f,0.f,0.f,0.f},{0.f,0.f,0.f,0.f}},
                       {{0.f,0.f,0.f,0.f},{0.f,0.f,0.f,0.f}}};

    const int arow = tid >> 2, acg = tid & 3;                 // A staging: 64 rows x 4 chunks
    const float* asrc = latent + (size_t)(m0 + arow) * IN_F + acg * 8;
    const int bkg = tid >> 6, bl = tid & 63;                  // B staging: 4 kg x 64 n

    for (int k0 = 0; k0 < IN_F; k0 += 32) {
        // --- stage A: fp32 -> bf16 into LDS [64][40]
        float4 a0 = *(const float4*)(asrc + k0);
        float4 a1 = *(const float4*)(asrc + k0 + 4);
        union { ushort u[8]; uint4 v; } pk;
        pk.u[0] = f2bf(a0.x); pk.u[1] = f2bf(a0.y); pk.u[2] = f2bf(a0.z); pk.u[3] = f2bf(a0.w);
        pk.u[4] = f2bf(a1.x); pk.u[5] = f2bf(a1.y); pk.u[6] = f2bf(a1.z); pk.u[7] = f2bf(a1.w);
        *(uint4*)&lA[arow * 40 + acg * 8] = pk.v;
        // --- stage B: contiguous 16B copy (already packed [k8][n][j])
        const uint4* bsrc = (const uint4*)(wp + ((size_t)(k0 / 8 + bkg) * OUT_F + n0) * 8) + bl;
        *(uint4*)&lB[(bkg * 64 + bl) * 8] = *bsrc;
        __syncthreads();

        // --- fragments + 4 MFMAs
        short8 af0 = *(short8*)&lA[(wm * 32 + l16) * 40 + quad * 8];
        short8 af1 = *(short8*)&lA[(wm * 32 + 16 + l16) * 40 + quad * 8];
        short8 bf0 = *(short8*)&lB[(quad * 64 + wn * 32 + l16) * 8];
        short8 bf1 = *(short8*)&lB[(quad * 64 + wn * 32 + 16 + l16) * 8];
        acc[0][0] = __builtin_amdgcn_mfma_f32_16x16x32_bf16(af0, bf0, acc[0][0], 0, 0, 0);
        acc[0][1] = __builtin_amdgcn_mfma_f32_16x16x32_bf16(af0, bf1, acc[0][1], 0, 0, 0);
        acc[1][0] = __builtin_amdgcn_mfma_f32_16x16x32_bf16(af1, bf0, acc[1][0], 0, 0, 0);
        acc[1][1] = __builtin_amdgcn_mfma_f32_16x16x32_bf16(af1, bf1, acc[1][1], 0, 0, 0);
        __syncthreads();
    }

    // --- epilogue: int_sum from true_sum, accumulate (pred - int_sum)^2
    float lsum = 0.f;
    #pragma unroll
    for (int fm = 0; fm < 2; fm++)
    #pragma unroll
    for (int fn = 0; fn < 2; fn++)
    #pragma unroll
    for (int r = 0; r < 4; r++) {
        int m = m0 + wm * 32 + fm * 16 + quad * 4 + r;
        int n = n0 + wn * 32 + fn * 16 + l16;
        const float* ts = tsum + (size_t)m * OUTB + (size_t)n * 8;
        float4 t0 = *(const float4*)(ts);
        float4 t1 = *(const float4*)(ts + 4);
        float isum = t0.x + 2.f * t0.y + 4.f * t0.z + 8.f * t0.w
                   + 16.f * t1.x + 32.f * t1.y + 64.f * t1.z - 128.f * t1.w;
        float d = acc[fm][fn][r] - isum;
        lsum += d * d;
    }

    float wsum = waveReduceSum(lsum);
    __shared__ float red[4];
    if ((tid & 63) == 0) red[tid >> 6] = wsum;
    __syncthreads();
    if (tid == 0) atomicAdd(accum + 0, red[0] + red[1] + red[2] + red[3]);
}

__global__ void k_fin(const float* __restrict__ accum, float* __restrict__ out) {
    float recon = accum[0] / ((float)(BATCH * OUT_F) * 255.f * 255.f);
    float reg   = 0.001f * accum[1] / (float)((size_t)IN_F * OUTB);
    out[0] = recon + reg;
    out[1] = recon;
    out[2] = reg;
}

extern "C" void kernel_launch(void* const* d_in, const int* in_sizes, int n_in,
                              void* d_out, int out_size, void* d_ws, size_t ws_size,
                              hipStream_t stream) {
    const float* latent = (const float*)d_in[0];   // [1024, 4096]
    const float* tsum   = (const float*)d_in[1];   // [1024, 6144]
    const float* weight = (const float*)d_in[2];   // [4096, 6144]
    float* out = (float*)d_out;                    // 3 floats
    float* accum = (float*)d_ws;                   // [recon_sum, reg_sum]
    ushort* wp = (ushort*)((char*)d_ws + 256);     // packed bf16 int_weights, 6.3 MB

    k_init<<<1, 1, 0, stream>>>(accum);
    k_weights<<<(512 * OUT_F) / 256, 256, 0, stream>>>(weight, wp, accum);
    k_gemm<<<dim3(OUT_F / 64, BATCH / 64), 256, 0, stream>>>(latent, wp, tsum, accum);
    k_fin<<<1, 1, 0, stream>>>(accum, out);
}

// Round 2
// 221.173 us; speedup vs baseline: 1.2411x; 1.2411x over previous
//
#include <hip/hip_runtime.h>
#include <hip/hip_bf16.h>
#include <stdint.h>

#define IN_F   4096
#define OUT_F  768
#define OUTB   (OUT_F * 8)       // 6144
#define BATCH  1024
#define SPLITK 4
#define KSPAN  (IN_F / SPLITK)   // 1024
#define NIT    (KSPAN / 32)      // 32

typedef short short8  __attribute__((ext_vector_type(8)));
typedef float f32x4   __attribute__((ext_vector_type(4)));
typedef unsigned int u32;

__device__ __forceinline__ ushort f2bf(float f) {
    uint32_t u = __builtin_bit_cast(uint32_t, f);
    u += 0x7FFFu + ((u >> 16) & 1u);
    return (ushort)(u >> 16);
}

__device__ __forceinline__ float waveReduceSum(float v) {
    #pragma unroll
    for (int off = 32; off > 0; off >>= 1) v += __shfl_down(v, off, 64);
    return v;
}

__device__ __forceinline__ void glds16(const void* g, void* l) {
    __builtin_amdgcn_global_load_lds(
        (const __attribute__((address_space(1))) u32*)g,
        (__attribute__((address_space(3))) u32*)l, 16, 0, 0);
}

// ws layout (bytes):
//   0        : accum[2]  (recon_sum, reg_sum)
//   256      : pred  float[1024*768]            (3 MB)
//   3146240  : wp    ushort[IN_F*OUT_F] packed  (6.29 MB)   [(k/8)][n][k%8]
//   9437696  : labf  ushort[1024*4096]          (8.39 MB)   bf16 latent row-major
#define WS_PRED  256
#define WS_WP    (WS_PRED + 3145728)
#define WS_LABF  (WS_WP + 6291456)

// k_prep: zero accum+pred, convert latent fp32 -> bf16
__global__ __launch_bounds__(256) void k_prep(const float* __restrict__ latent,
                                              float* __restrict__ accum,
                                              float* __restrict__ pred,
                                              ushort* __restrict__ labf) {
    int i = blockIdx.x * 256 + threadIdx.x;          // 524288 threads
    if (i == 0) { accum[0] = 0.f; accum[1] = 0.f; }
    if (i < (BATCH * OUT_F) / 4) ((float4*)pred)[i] = make_float4(0.f, 0.f, 0.f, 0.f);
    float4 a0 = ((const float4*)latent)[2 * i];
    float4 a1 = ((const float4*)latent)[2 * i + 1];
    union { ushort u[8]; uint4 v; } pk;
    pk.u[0] = f2bf(a0.x); pk.u[1] = f2bf(a0.y); pk.u[2] = f2bf(a0.z); pk.u[3] = f2bf(a0.w);
    pk.u[4] = f2bf(a1.x); pk.u[5] = f2bf(a1.y); pk.u[6] = f2bf(a1.z); pk.u[7] = f2bf(a1.w);
    ((uint4*)labf)[i] = pk.v;
}

// k_weights: int_weights (bf16 packed [k/8][n][k%8]) + reg_loss partial sums
__global__ __launch_bounds__(256) void k_weights(const float* __restrict__ w,
                                                 ushort* __restrict__ wp,
                                                 float* __restrict__ accum) {
    int t  = blockIdx.x * 256 + threadIdx.x;
    int o  = t % OUT_F;
    int i8 = t / OUT_F;
    const float* src = w + (size_t)(i8 * 8) * OUTB + (size_t)o * 8;

    const float P[8] = {1.f, 2.f, 4.f, 8.f, 16.f, 32.f, 64.f, -128.f};
    float regsum = 0.f;
    union { ushort u[8]; uint4 v; } pk;

    #pragma unroll
    for (int r = 0; r < 8; r++) {
        float4 a = *(const float4*)(src + (size_t)r * OUTB);
        float4 b = *(const float4*)(src + (size_t)r * OUTB + 4);
        float x[8] = {a.x, a.y, a.z, a.w, b.x, b.y, b.z, b.w};
        float iw = 0.f;
        #pragma unroll
        for (int j = 0; j < 8; j++) {
            float p = __builtin_amdgcn_rcpf(1.f + __expf(-x[j]));   // fast sigmoid
            iw += p * P[j];
            regsum += fminf(p, 1.f - p);
        }
        pk.u[r] = f2bf(iw);
    }
    *(uint4*)(wp + ((size_t)i8 * OUT_F + o) * 8) = pk.v;

    float ws = waveReduceSum(regsum);
    __shared__ float red[4];
    int lane = threadIdx.x & 63, wv = threadIdx.x >> 6;
    if (lane == 0) red[wv] = ws;
    __syncthreads();
    if (threadIdx.x == 0) atomicAdd(accum + 1, red[0] + red[1] + red[2] + red[3]);
}

// k_gemm: split-K bf16 MFMA GEMM, 64x64 tile, BK=32, double-buffered,
// B staged via global_load_lds. Partials atomicAdd'ed into pred.
__global__ __launch_bounds__(256) void k_gemm(const ushort* __restrict__ labf,
                                              const ushort* __restrict__ wp,
                                              float* __restrict__ pred) {
    // lA: [64 rows][40] ushorts (pad -> 2-way banks). chunk(row,q) at row*40+q*8
    // lB: 4 planes, plane stride 1032 ushorts (2064 B, bank shift 4/plane)
    __shared__ __align__(16) ushort lA[2][64 * 40];
    __shared__ __align__(16) ushort lB[2][4 * 1032];

    const int tid  = threadIdx.x;
    const int n0   = blockIdx.x * 64;
    const int m0   = blockIdx.y * 64;
    const int kbase = blockIdx.z * KSPAN;
    const int lane = tid & 63, w = tid >> 6;
    const int wm = w >> 1, wn = w & 1;
    const int quad = lane >> 4, l16 = lane & 15;

    f32x4 acc[2][2] = {{{0.f,0.f,0.f,0.f},{0.f,0.f,0.f,0.f}},
                       {{0.f,0.f,0.f,0.f},{0.f,0.f,0.f,0.f}}};

    // A staging: thread -> (row ar, chunk ac); 16B per thread per iter
    const int ar = tid >> 2, ac = tid & 3;
    const ushort* aptr = labf + (size_t)(m0 + ar) * IN_F + kbase + ac * 8;
    // B staging: wave w stages plane kg=w; lane l -> n0+l (16B contiguous)
    const ushort* bptr = wp + ((size_t)(kbase / 8 + w) * OUT_F + n0 + lane) * 8;

    int buf = 0;
    // prologue: stage iter 0
    glds16(bptr, &lB[0][w * 1032]);
    uint4 aR = *(const uint4*)aptr;
    *(uint4*)&lA[0][ar * 40 + ac * 8] = aR;
    __syncthreads();

    for (int it = 0; it < NIT; ++it) {
        const int nxt = buf ^ 1;
        if (it + 1 < NIT) {
            glds16(bptr + (size_t)(it + 1) * 4 * OUT_F * 8, &lB[nxt][w * 1032]);
            aR = *(const uint4*)(aptr + (it + 1) * 32);
        }
        short8 af0 = *(short8*)&lA[buf][(wm * 32 + l16) * 40 + quad * 8];
        short8 af1 = *(short8*)&lA[buf][(wm * 32 + 16 + l16) * 40 + quad * 8];
        short8 bf0 = *(short8*)&lB[buf][quad * 1032 + (wn * 32 + l16) * 8];
        short8 bf1 = *(short8*)&lB[buf][quad * 1032 + (wn * 32 + 16 + l16) * 8];
        acc[0][0] = __builtin_amdgcn_mfma_f32_16x16x32_bf16(af0, bf0, acc[0][0], 0, 0, 0);
        acc[0][1] = __builtin_amdgcn_mfma_f32_16x16x32_bf16(af0, bf1, acc[0][1], 0, 0, 0);
        acc[1][0] = __builtin_amdgcn_mfma_f32_16x16x32_bf16(af1, bf0, acc[1][0], 0, 0, 0);
        acc[1][1] = __builtin_amdgcn_mfma_f32_16x16x32_bf16(af1, bf1, acc[1][1], 0, 0, 0);
        if (it + 1 < NIT) *(uint4*)&lA[nxt][ar * 40 + ac * 8] = aR;
        __syncthreads();
        buf = nxt;
    }

    // epilogue: atomic-accumulate partial tile into pred
    #pragma unroll
    for (int fm = 0; fm < 2; fm++)
    #pragma unroll
    for (int fn = 0; fn < 2; fn++)
    #pragma unroll
    for (int r = 0; r < 4; r++) {
        int m = m0 + wm * 32 + fm * 16 + quad * 4 + r;
        int n = n0 + wn * 32 + fn * 16 + l16;
        atomicAdd(&pred[(size_t)m * OUT_F + n], acc[fm][fn][r]);
    }
}

// k_epi: recon = sum over (m,n) of (pred - int_sum)^2
__global__ __launch_bounds__(256) void k_epi(const float* __restrict__ pred,
                                             const float* __restrict__ tsum,
                                             float* __restrict__ accum) {
    int i = blockIdx.x * 256 + threadIdx.x;        // 196608 threads, 4 n each
    int m = i / (OUT_F / 4);
    int c = i % (OUT_F / 4);
    float4 p = ((const float4*)pred)[(size_t)m * (OUT_F / 4) + c];
    const float* ts = tsum + (size_t)m * OUTB + (size_t)c * 32;
    float lsum = 0.f;
    float pv[4] = {p.x, p.y, p.z, p.w};
    #pragma unroll
    for (int j = 0; j < 4; j++) {
        float4 t0 = *(const float4*)(ts + j * 8);
        float4 t1 = *(const float4*)(ts + j * 8 + 4);
        float isum = t0.x + 2.f * t0.y + 4.f * t0.z + 8.f * t0.w
                   + 16.f * t1.x + 32.f * t1.y + 64.f * t1.z - 128.f * t1.w;
        float d = pv[j] - isum;
        lsum += d * d;
    }
    float wsum = waveReduceSum(lsum);
    __shared__ float red[4];
    if ((threadIdx.x & 63) == 0) red[threadIdx.x >> 6] = wsum;
    __syncthreads();
    if (threadIdx.x == 0) atomicAdd(accum + 0, red[0] + red[1] + red[2] + red[3]);
}

__global__ void k_fin(const float* __restrict__ accum, float* __restrict__ out) {
    float recon = accum[0] / ((float)(BATCH * OUT_F) * 255.f * 255.f);
    float reg   = 0.001f * accum[1] / (float)((size_t)IN_F * OUTB);
    out[0] = recon + reg;
    out[1] = recon;
    out[2] = reg;
}

extern "C" void kernel_launch(void* const* d_in, const int* in_sizes, int n_in,
                              void* d_out, int out_size, void* d_ws, size_t ws_size,
                              hipStream_t stream) {
    const float* latent = (const float*)d_in[0];   // [1024, 4096]
    const float* tsum   = (const float*)d_in[1];   // [1024, 6144]
    const float* weight = (const float*)d_in[2];   // [4096, 6144]
    float* out   = (float*)d_out;
    float* accum = (float*)d_ws;
    float* pred  = (float*)((char*)d_ws + WS_PRED);
    ushort* wp   = (ushort*)((char*)d_ws + WS_WP);
    ushort* labf = (ushort*)((char*)d_ws + WS_LABF);

    k_prep<<<2048, 256, 0, stream>>>(latent, accum, pred, labf);
    k_weights<<<(512 * OUT_F) / 256, 256, 0, stream>>>(weight, wp, accum);
    k_gemm<<<dim3(OUT_F / 64, BATCH / 64, SPLITK), 256, 0, stream>>>(labf, wp, pred);
    k_epi<<<(BATCH * OUT_F / 4) / 256, 256, 0, stream>>>(pred, tsum, accum);
    k_fin<<<1, 1, 0, stream>>>(accum, out);
}

// Round 3
// 204.510 us; speedup vs baseline: 1.3422x; 1.0815x over previous
//
#include <hip/hip_runtime.h>
#include <hip/hip_bf16.h>
#include <stdint.h>

#define IN_F   4096
#define OUT_F  768
#define OUTB   (OUT_F * 8)       // 6144
#define BATCH  1024
#define SPLITK 4
#define KSPAN  (IN_F / SPLITK)   // 1024
#define NIT    (KSPAN / 32)      // 32
#define PLANE  (BATCH * OUT_F)   // 786432 floats per split-K partial plane

typedef short short8  __attribute__((ext_vector_type(8)));
typedef float f32x4   __attribute__((ext_vector_type(4)));
typedef unsigned int u32;

__device__ __forceinline__ ushort f2bf(float f) {
    uint32_t u = __builtin_bit_cast(uint32_t, f);
    u += 0x7FFFu + ((u >> 16) & 1u);
    return (ushort)(u >> 16);
}

__device__ __forceinline__ float waveReduceSum(float v) {
    #pragma unroll
    for (int off = 32; off > 0; off >>= 1) v += __shfl_down(v, off, 64);
    return v;
}

__device__ __forceinline__ void glds16(const void* g, void* l) {
    __builtin_amdgcn_global_load_lds(
        (const __attribute__((address_space(1))) u32*)g,
        (__attribute__((address_space(3))) u32*)l, 16, 0, 0);
}

// ws layout (bytes) — no buffer needs zero-init (pure writes + partial arrays):
//   0        : predp  float[4][1024*768]  split-K partial planes (12.58 MB)
//   12582912 : wp     ushort[IN_F*OUT_F]  packed [(k/8)][n][k%8]  (6.29 MB)
//   18874368 : labf   ushort[1024*4096]   bf16 latent row-major   (8.39 MB)
//   27262976 : regpart float[1536]        per-block reg-loss partials
//   27269120 : sqpart  float[3072]        per-block recon partials
#define WS_WP    12582912
#define WS_LABF  18874368
#define WS_REGP  27262976
#define WS_SQP   27269120

// k_weights: blocks [0,1536) -> int_weights (bf16 packed) + reg partials;
//            blocks [1536,2048) -> latent fp32 -> bf16 conversion (rides the
//            same dispatch since both paths are HBM-bound; no serial k_prep).
__global__ __launch_bounds__(256) void k_weights(const float* __restrict__ w,
                                                 const float* __restrict__ latent,
                                                 ushort* __restrict__ wp,
                                                 ushort* __restrict__ labf,
                                                 float* __restrict__ regpart) {
    if (blockIdx.x >= 1536) {
        // --- latent conversion: 512 blocks, 131072 threads, 4 uint4 each
        int t = (blockIdx.x - 1536) * 256 + threadIdx.x;
        const float4* src = (const float4*)latent;
        uint4* dst = (uint4*)labf;
        #pragma unroll
        for (int j = 0; j < 4; j++) {
            int o = j * 131072 + t;              // uint4 index, lane-consecutive
            float4 a0 = src[2 * o];
            float4 a1 = src[2 * o + 1];
            union { ushort u[8]; uint4 v; } pk;
            pk.u[0] = f2bf(a0.x); pk.u[1] = f2bf(a0.y); pk.u[2] = f2bf(a0.z); pk.u[3] = f2bf(a0.w);
            pk.u[4] = f2bf(a1.x); pk.u[5] = f2bf(a1.y); pk.u[6] = f2bf(a1.z); pk.u[7] = f2bf(a1.w);
            dst[o] = pk.v;
        }
        return;
    }

    int t  = blockIdx.x * 256 + threadIdx.x;     // 512*768 threads
    int o  = t % OUT_F;
    int i8 = t / OUT_F;
    const float* src = w + (size_t)(i8 * 8) * OUTB + (size_t)o * 8;

    const float P[8] = {1.f, 2.f, 4.f, 8.f, 16.f, 32.f, 64.f, -128.f};
    float regsum = 0.f;
    union { ushort u[8]; uint4 v; } pk;

    #pragma unroll
    for (int r = 0; r < 8; r++) {
        float4 a = *(const float4*)(src + (size_t)r * OUTB);
        float4 b = *(const float4*)(src + (size_t)r * OUTB + 4);
        float x[8] = {a.x, a.y, a.z, a.w, b.x, b.y, b.z, b.w};
        float iw = 0.f;
        #pragma unroll
        for (int j = 0; j < 8; j++) {
            float p = __builtin_amdgcn_rcpf(1.f + __expf(-x[j]));   // fast sigmoid
            iw += p * P[j];
            regsum += fminf(p, 1.f - p);
        }
        pk.u[r] = f2bf(iw);
    }
    *(uint4*)(wp + ((size_t)i8 * OUT_F + o) * 8) = pk.v;

    float ws = waveReduceSum(regsum);
    __shared__ float red[4];
    int lane = threadIdx.x & 63, wv = threadIdx.x >> 6;
    if (lane == 0) red[wv] = ws;
    __syncthreads();
    if (threadIdx.x == 0) regpart[blockIdx.x] = red[0] + red[1] + red[2] + red[3];
}

// k_gemm: split-K bf16 MFMA GEMM, 64x64 tile, BK=32, double-buffered,
// B staged via global_load_lds. Partials stored to disjoint planes (no atomics).
__global__ __launch_bounds__(256) void k_gemm(const ushort* __restrict__ labf,
                                              const ushort* __restrict__ wp,
                                              float* __restrict__ predp) {
    __shared__ __align__(16) ushort lA[2][64 * 40];
    __shared__ __align__(16) ushort lB[2][4 * 1032];

    const int tid  = threadIdx.x;
    const int n0   = blockIdx.x * 64;
    const int m0   = blockIdx.y * 64;
    const int kbase = blockIdx.z * KSPAN;
    const int lane = tid & 63, w = tid >> 6;
    const int wm = w >> 1, wn = w & 1;
    const int quad = lane >> 4, l16 = lane & 15;

    f32x4 acc[2][2] = {{{0.f,0.f,0.f,0.f},{0.f,0.f,0.f,0.f}},
                       {{0.f,0.f,0.f,0.f},{0.f,0.f,0.f,0.f}}};

    const int ar = tid >> 2, ac = tid & 3;
    const ushort* aptr = labf + (size_t)(m0 + ar) * IN_F + kbase + ac * 8;
    const ushort* bptr = wp + ((size_t)(kbase / 8 + w) * OUT_F + n0 + lane) * 8;

    int buf = 0;
    glds16(bptr, &lB[0][w * 1032]);
    uint4 aR = *(const uint4*)aptr;
    *(uint4*)&lA[0][ar * 40 + ac * 8] = aR;
    __syncthreads();

    for (int it = 0; it < NIT; ++it) {
        const int nxt = buf ^ 1;
        if (it + 1 < NIT) {
            glds16(bptr + (size_t)(it + 1) * 4 * OUT_F * 8, &lB[nxt][w * 1032]);
            aR = *(const uint4*)(aptr + (it + 1) * 32);
        }
        short8 af0 = *(short8*)&lA[buf][(wm * 32 + l16) * 40 + quad * 8];
        short8 af1 = *(short8*)&lA[buf][(wm * 32 + 16 + l16) * 40 + quad * 8];
        short8 bf0 = *(short8*)&lB[buf][quad * 1032 + (wn * 32 + l16) * 8];
        short8 bf1 = *(short8*)&lB[buf][quad * 1032 + (wn * 32 + 16 + l16) * 8];
        acc[0][0] = __builtin_amdgcn_mfma_f32_16x16x32_bf16(af0, bf0, acc[0][0], 0, 0, 0);
        acc[0][1] = __builtin_amdgcn_mfma_f32_16x16x32_bf16(af0, bf1, acc[0][1], 0, 0, 0);
        acc[1][0] = __builtin_amdgcn_mfma_f32_16x16x32_bf16(af1, bf0, acc[1][0], 0, 0, 0);
        acc[1][1] = __builtin_amdgcn_mfma_f32_16x16x32_bf16(af1, bf1, acc[1][1], 0, 0, 0);
        if (it + 1 < NIT) *(uint4*)&lA[nxt][ar * 40 + ac * 8] = aR;
        __syncthreads();
        buf = nxt;
    }

    float* plane = predp + (size_t)blockIdx.z * PLANE;
    #pragma unroll
    for (int fm = 0; fm < 2; fm++)
    #pragma unroll
    for (int fn = 0; fn < 2; fn++)
    #pragma unroll
    for (int r = 0; r < 4; r++) {
        int m = m0 + wm * 32 + fm * 16 + quad * 4 + r;
        int n = n0 + wn * 32 + fn * 16 + l16;
        plane[(size_t)m * OUT_F + n] = acc[fm][fn][r];
    }
}

// k_epi: grid (3, 1024); one thread per (m,n). Sums 4 split-K planes,
// computes int_sum from tsum, accumulates (pred-int_sum)^2 per block.
__global__ __launch_bounds__(256) void k_epi(const float* __restrict__ predp,
                                             const float* __restrict__ tsum,
                                             float* __restrict__ sqpart) {
    int n = blockIdx.x * 256 + threadIdx.x;
    int m = blockIdx.y;
    size_t idx = (size_t)m * OUT_F + n;
    float p = predp[idx] + predp[idx + PLANE] + predp[idx + 2 * PLANE] + predp[idx + 3 * PLANE];
    const float* ts = tsum + (size_t)m * OUTB + (size_t)n * 8;
    float4 t0 = *(const float4*)ts;
    float4 t1 = *(const float4*)(ts + 4);
    float isum = t0.x + 2.f * t0.y + 4.f * t0.z + 8.f * t0.w
               + 16.f * t1.x + 32.f * t1.y + 64.f * t1.z - 128.f * t1.w;
    float d = p - isum;
    float lsum = d * d;

    float wsum = waveReduceSum(lsum);
    __shared__ float red[4];
    if ((threadIdx.x & 63) == 0) red[threadIdx.x >> 6] = wsum;
    __syncthreads();
    if (threadIdx.x == 0)
        sqpart[blockIdx.y * 3 + blockIdx.x] = red[0] + red[1] + red[2] + red[3];
}

// k_fin: sum 1536 reg partials + 3072 sq partials, write the 3 outputs.
__global__ __launch_bounds__(256) void k_fin(const float* __restrict__ regpart,
                                             const float* __restrict__ sqpart,
                                             float* __restrict__ out) {
    int tid = threadIdx.x;
    float r = 0.f, s = 0.f;
    #pragma unroll
    for (int j = 0; j < 6; j++) r += regpart[tid + j * 256];
    #pragma unroll
    for (int j = 0; j < 12; j++) s += sqpart[tid + j * 256];
    r = waveReduceSum(r);
    s = waveReduceSum(s);
    __shared__ float redR[4], redS[4];
    int lane = tid & 63, wv = tid >> 6;
    if (lane == 0) { redR[wv] = r; redS[wv] = s; }
    __syncthreads();
    if (tid == 0) {
        float R = redR[0] + redR[1] + redR[2] + redR[3];
        float S = redS[0] + redS[1] + redS[2] + redS[3];
        float recon = S / ((float)(BATCH * OUT_F) * 255.f * 255.f);
        float reg   = 0.001f * R / (float)((size_t)IN_F * OUTB);
        out[0] = recon + reg;
        out[1] = recon;
        out[2] = reg;
    }
}

extern "C" void kernel_launch(void* const* d_in, const int* in_sizes, int n_in,
                              void* d_out, int out_size, void* d_ws, size_t ws_size,
                              hipStream_t stream) {
    const float* latent = (const float*)d_in[0];   // [1024, 4096]
    const float* tsum   = (const float*)d_in[1];   // [1024, 6144]
    const float* weight = (const float*)d_in[2];   // [4096, 6144]
    float* out     = (float*)d_out;
    float* predp   = (float*)d_ws;
    ushort* wp     = (ushort*)((char*)d_ws + WS_WP);
    ushort* labf   = (ushort*)((char*)d_ws + WS_LABF);
    float* regpart = (float*)((char*)d_ws + WS_REGP);
    float* sqpart  = (float*)((char*)d_ws + WS_SQP);

    k_weights<<<2048, 256, 0, stream>>>(weight, latent, wp, labf, regpart);
    k_gemm<<<dim3(OUT_F / 64, BATCH / 64, SPLITK), 256, 0, stream>>>(labf, wp, predp);
    k_epi<<<dim3(3, BATCH), 256, 0, stream>>>(predp, tsum, sqpart);
    k_fin<<<1, 256, 0, stream>>>(regpart, sqpart, out);
}